// Round 10
// baseline (2152.917 us; speedup 1.0000x reference)
//
#include <hip/hip_runtime.h>

// ---------------- problem constants ----------------
#define T_STEPS 512
#define BATCH_N 256
#define IDIM    128
#define NDIM    1024
#define ODIM    10

// 128 WGs = 16 batch-groups (16 rows) x 8 col-slices (128 cols), 512 threads
// = 8 waves (4 K-quarters x 2 ct-groups). W in regs (128/lane).
// Transport: SELF-TAGGED u32 words {bf16<<16 | step_tag} (R5-proven: no drain,
// no flags, fire-and-forget publish), parity double-buffered, sc0 sc1, with
// R9-proven COALESCED cooperative gather -> swizzled LDS. Per-wave retry.
#define THREADS 512
#define GAIN 0.03125f

// ---------------- workspace layout (bytes) ----------------
#define YBUF_OFF    (33554432ull)                 // u32 [2][16][16][1024] = 2 MB
#define YPAR_WORDS  (262144u)                     // u32 per parity
#define XT_OFF      (YBUF_OFF + 2097152ull)
#define XT_BYTES    (1048576ull)                  // fp32 [256][1024]
#define WS_NEED     (XT_OFF + XT_BYTES)

typedef short    s16x8 __attribute__((ext_vector_type(8)));
typedef float    f32x4 __attribute__((ext_vector_type(4)));
typedef unsigned u32x4 __attribute__((ext_vector_type(4)));
typedef unsigned u32x2 __attribute__((ext_vector_type(2)));

__device__ __forceinline__ unsigned short f2bf(float f) {
  unsigned u = __builtin_bit_cast(unsigned, f);
  u += 0x7fffu + ((u >> 16) & 1u);               // RTNE
  return (unsigned short)(u >> 16);
}
__device__ __forceinline__ unsigned umin2(unsigned a, unsigned b) { return a < b ? a : b; }

// ---------------- batch fp32 -> bf16 prepass ----------------
__global__ void horn_convert(const float* __restrict__ src, unsigned short* __restrict__ dst) {
  size_t gid = (size_t)blockIdx.x * 256 + threadIdx.x;
  const f32x4* s4 = reinterpret_cast<const f32x4*>(src) + gid * 2;
  f32x4 a = s4[0], b = s4[1];
  u32x4 o;
  o[0] = (unsigned)f2bf(a[0]) | ((unsigned)f2bf(a[1]) << 16);
  o[1] = (unsigned)f2bf(a[2]) | ((unsigned)f2bf(a[3]) << 16);
  o[2] = (unsigned)f2bf(b[0]) | ((unsigned)f2bf(b[1]) << 16);
  o[3] = (unsigned)f2bf(b[2]) | ((unsigned)f2bf(b[3]) << 16);
  reinterpret_cast<u32x4*>(dst)[gid] = o;
}

// ---------------- persistent recurrent kernel ----------------
// LDS: [0,32768)    y-stage bf16 [16 rows][1024 k], XOR-swizzled
//      [32768,65536) red[4 ki][8 ct][64 lane] f32x4
__launch_bounds__(THREADS, 2)
__global__ void horn_persistent(const unsigned short* __restrict__ batchbf,
                                const float* __restrict__ i2h_w,
                                const float* __restrict__ i2h_b,
                                const float* __restrict__ h2h_w,
                                const float* __restrict__ h2h_b,
                                unsigned* ybuf,           // u32 [2][16][16][1024]
                                float* xT)                // [256][1024] fp32
{
  extern __shared__ char smem[];
  char*  ylds = smem;                              // 32 KB
  f32x4* red  = (f32x4*)(smem + 32768);            // 32 KB

  const int tid  = threadIdx.x;
  const int lane = tid & 63;
  const int wv   = tid >> 6;           // 0..7
  const int ki   = wv & 3;             // K-quarter [ki*256, +256)
  const int ci   = wv >> 2;            // ct-group: cts [ci*4, ci*4+4)
  const int g    = blockIdx.x & 15;    // batch group (16 rows)
  const int s    = blockIdx.x >> 4;    // col-slice 0..7 (128 cols)
  const int l15  = lane & 15;
  const int kb   = lane >> 4;
  const int ct_own = ci * 4 + ki;      // owned ct (bijective over 8 waves)
  const int jc   = s * 128 + ct_own * 16 + l15;    // owned output column

  // ---- W fragments: 4 ct x 8 kc (K-quarter ki), xGAIN = 128 VGPRs ----
  s16x8 wfrag[4][8];
  #pragma unroll
  for (int j = 0; j < 4; ++j) {
    #pragma unroll
    for (int kc = 0; kc < 8; ++kc) {
      const float* gp = h2h_w + (size_t)(s * 128 + (ci * 4 + j) * 16 + l15) * NDIM
                        + ki * 256 + kc * 32 + kb * 8;
      f32x4 a = *reinterpret_cast<const f32x4*>(gp);
      f32x4 b = *reinterpret_cast<const f32x4*>(gp + 4);
      s16x8 v;
      v[0] = (short)f2bf(a[0]*GAIN); v[1] = (short)f2bf(a[1]*GAIN);
      v[2] = (short)f2bf(a[2]*GAIN); v[3] = (short)f2bf(a[3]*GAIN);
      v[4] = (short)f2bf(b[0]*GAIN); v[5] = (short)f2bf(b[1]*GAIN);
      v[6] = (short)f2bf(b[2]*GAIN); v[7] = (short)f2bf(b[3]*GAIN);
      wfrag[j][kc] = v;
    }
  }

  // ---- i2h B-frags for owned column + fused bias ----
  s16x8 i2hf[4];
  #pragma unroll
  for (int kc = 0; kc < 4; ++kc) {
    const float* gp = i2h_w + (size_t)jc * IDIM + kc * 32 + kb * 8;
    s16x8 v;
    #pragma unroll
    for (int e = 0; e < 8; ++e) v[e] = (short)f2bf(gp[e]);
    i2hf[kc] = v;
  }
  const float bias = i2h_b[jc] + GAIN * h2h_b[jc];

  // ---- batch A-frags for t=0 ----
  s16x8 bfr[4];
  {
    const unsigned short* bp = batchbf + ((size_t)g * 16 + l15) * IDIM + kb * 8;
    #pragma unroll
    for (int kc = 0; kc < 4; ++kc) bfr[kc] = *reinterpret_cast<const s16x8*>(bp + kc * 32);
  }

  float xs[4] = {0.f,0.f,0.f,0.f};
  float ys[4] = {0.f,0.f,0.f,0.f};

  const char* gb = (const char*)ybuf + (size_t)g * 65536 + (size_t)tid * 16;  // + p*1MB
  unsigned* pb0 = ybuf + (size_t)(g * 16 + kb * 4) * 1024 + jc;               // + pn*YPAR_WORDS

  for (int t = 0; t < T_STEPS; ++t) {
    const int p = t & 1, pn = p ^ 1;
    const char* a0 = gb + (size_t)p * 1048576;

    u32x4 g0, g1, g2, g3, g4, g5, g6, g7;
    #define GISSUE asm volatile( \
      "global_load_dwordx4 %0, %8, off sc0 sc1\n\t" \
      "global_load_dwordx4 %1, %9, off sc0 sc1\n\t" \
      "global_load_dwordx4 %2, %10, off sc0 sc1\n\t" \
      "global_load_dwordx4 %3, %11, off sc0 sc1\n\t" \
      "global_load_dwordx4 %4, %12, off sc0 sc1\n\t" \
      "global_load_dwordx4 %5, %13, off sc0 sc1\n\t" \
      "global_load_dwordx4 %6, %14, off sc0 sc1\n\t" \
      "global_load_dwordx4 %7, %15, off sc0 sc1" \
      : "=&v"(g0), "=&v"(g1), "=&v"(g2), "=&v"(g3), \
        "=&v"(g4), "=&v"(g5), "=&v"(g6), "=&v"(g7) \
      : "v"(a0), "v"(a0 + 8192), "v"(a0 + 16384), "v"(a0 + 24576), \
        "v"(a0 + 32768), "v"(a0 + 40960), "v"(a0 + 49152), "v"(a0 + 57344) \
      : "memory")

    // ---- issue first gather attempt, hide u-phase under it ----
    GISSUE;
    f32x4 uacc = {bias, bias, bias, bias};
    #pragma unroll
    for (int kc = 0; kc < 4; ++kc)
      uacc = __builtin_amdgcn_mfma_f32_16x16x32_bf16(bfr[kc], i2hf[kc], uacc, 0, 0, 0);

    // ---- per-wave retry: gather IS the poll (tags in low 16 bits) ----
    while (true) {
      asm volatile("s_waitcnt vmcnt(0)" ::: "memory");
      __builtin_amdgcn_sched_barrier(0);           // rule #18: no hoisting past the wait
      unsigned mn = 0xffffffffu;
      #define MN(v) mn = umin2(mn, umin2(umin2(v[0]&0xffffu, v[1]&0xffffu), umin2(v[2]&0xffffu, v[3]&0xffffu)));
      MN(g0) MN(g1) MN(g2) MN(g3) MN(g4) MN(g5) MN(g6) MN(g7)
      #undef MN
      if (__all((int)(mn >= (unsigned)t))) break;
      __builtin_amdgcn_s_sleep(2);
      GISSUE;
    }
    #undef GISSUE

    // ---- repack (hi16) + stage to LDS, XOR-swizzled ----
    #define STG(r, vr) { \
      u32x2 w_; \
      w_[0] = __builtin_amdgcn_perm(vr[1], vr[0], 0x07060302u); \
      w_[1] = __builtin_amdgcn_perm(vr[3], vr[2], 0x07060302u); \
      int B_ = (r) * 8192 + tid * 16; \
      int off_ = (B_ >> 1) ^ ((((B_ >> 12) & 7)) << 4); \
      *reinterpret_cast<u32x2*>(ylds + off_) = w_; }
    STG(0, g0) STG(1, g1) STG(2, g2) STG(3, g3)
    STG(4, g4) STG(5, g5) STG(6, g6) STG(7, g7)
    #undef STG
    __syncthreads();                               // bar1: tile ready

    // ---- rec partials: 4 ct x 8 kc MFMAs, A-frags from LDS ----
    f32x4 c0 = {0,0,0,0}, c1 = {0,0,0,0}, c2 = {0,0,0,0}, c3 = {0,0,0,0};
    #pragma unroll
    for (int kc = 0; kc < 8; ++kc) {
      int boff = (l15 * 2048 + ki * 512 + kc * 64 + kb * 16) ^ ((l15 & 7) << 4);
      s16x8 a = *reinterpret_cast<const s16x8*>(ylds + boff);
      c0 = __builtin_amdgcn_mfma_f32_16x16x32_bf16(a, wfrag[0][kc], c0, 0, 0, 0);
      c1 = __builtin_amdgcn_mfma_f32_16x16x32_bf16(a, wfrag[1][kc], c1, 0, 0, 0);
      c2 = __builtin_amdgcn_mfma_f32_16x16x32_bf16(a, wfrag[2][kc], c2, 0, 0, 0);
      c3 = __builtin_amdgcn_mfma_f32_16x16x32_bf16(a, wfrag[3][kc], c3, 0, 0, 0);
    }

    // ---- cross-wave K-reduction ----
    red[((size_t)ki * 8 + ci * 4 + 0) * 64 + lane] = c0;
    red[((size_t)ki * 8 + ci * 4 + 1) * 64 + lane] = c1;
    red[((size_t)ki * 8 + ci * 4 + 2) * 64 + lane] = c2;
    red[((size_t)ki * 8 + ci * 4 + 3) * 64 + lane] = c3;
    __syncthreads();                               // bar2: partials ready
    f32x4 z = uacc;
    z += red[(0 * 8 + ct_own) * 64 + lane];
    z += red[(1 * 8 + ct_own) * 64 + lane];
    z += red[(2 * 8 + ct_own) * 64 + lane];
    z += red[(3 * 8 + ct_own) * 64 + lane];

    // ---- state update + self-tagged publish (fire-and-forget) ----
    const unsigned tag = (unsigned)(t + 1);
    unsigned* pb = pb0 + (size_t)pn * YPAR_WORDS;
    #define UPD(r) { \
      float z_ = z[r]; \
      float e_ = __expf(z_ + z_); \
      float th_ = fmaf(-2.0f, __builtin_amdgcn_rcpf(e_ + 1.0f), 1.0f); \
      float yn_ = ys[r] + 0.1f*(th_ - xs[r] - 0.2f*ys[r]); \
      xs[r] += 0.1f*yn_; ys[r] = yn_; \
      unsigned w_ = ((unsigned)f2bf(yn_) << 16) | tag; \
      unsigned* ad_ = pb + (r) * 1024; \
      asm volatile("global_store_dword %0, %1, off sc0 sc1" :: "v"(ad_), "v"(w_) : "memory"); }
    UPD(0) UPD(1) UPD(2) UPD(3)
    #undef UPD

    // ---- prefetch batch for t+1 (plain cached loads; drained by next retry) ----
    {
      const int tn = (t + 1 < T_STEPS) ? (t + 1) : t;
      const unsigned short* bp = batchbf + ((size_t)tn * BATCH_N + g * 16 + l15) * IDIM + kb * 8;
      #pragma unroll
      for (int kc = 0; kc < 4; ++kc) bfr[kc] = *reinterpret_cast<const s16x8*>(bp + kc * 32);
    }
  }

  // ---- write x_T (owned column, 4 rows) ----
  #pragma unroll
  for (int q = 0; q < 4; ++q) {
    int row = g * 16 + kb * 4 + q;
    xT[(size_t)row * NDIM + jc] = xs[q];
  }
}

// ---------------- final readout: out = x_T @ h2o^T + b ----------------
__global__ void horn_out(const float* __restrict__ xT, const float* __restrict__ h2o_w,
                         const float* __restrict__ h2o_b, float* __restrict__ out) {
  int b = blockIdx.x;
  int lane = threadIdx.x;                  // 64 threads
  float p[ODIM];
  #pragma unroll
  for (int o = 0; o < ODIM; ++o) p[o] = 0.f;
  for (int it = 0; it < NDIM / 64; ++it) {
    int n = it * 64 + lane;
    float xv = xT[(size_t)b * NDIM + n];
    #pragma unroll
    for (int o = 0; o < ODIM; ++o) p[o] += xv * h2o_w[o * NDIM + n];
  }
  #pragma unroll
  for (int o = 0; o < ODIM; ++o) {
    float v = p[o];
    #pragma unroll
    for (int off = 32; off >= 1; off >>= 1) v += __shfl_down(v, off, 64);
    if (lane == 0) out[b * ODIM + o] = v + h2o_b[o];
  }
}

__global__ void horn_fail(float* out) {    // loud sentinel if ws too small
  int i = blockIdx.x * 256 + threadIdx.x;
  if (i < BATCH_N * ODIM) out[i] = 12345.0f;
}

extern "C" void kernel_launch(void* const* d_in, const int* in_sizes, int n_in,
                              void* d_out, int out_size, void* d_ws, size_t ws_size,
                              hipStream_t stream) {
  const float* batch = (const float*)d_in[0];
  const float* i2h_w = (const float*)d_in[1];
  const float* i2h_b = (const float*)d_in[2];
  const float* h2h_w = (const float*)d_in[3];
  const float* h2h_b = (const float*)d_in[4];
  const float* h2o_w = (const float*)d_in[5];
  const float* h2o_b = (const float*)d_in[6];
  float* out = (float*)d_out;
  char* ws = (char*)d_ws;

  if (ws_size < WS_NEED) {
    horn_fail<<<16, 256, 0, stream>>>(out);
    return;
  }

  (void)hipFuncSetAttribute(reinterpret_cast<const void*>(horn_persistent),
                            hipFuncAttributeMaxDynamicSharedMemorySize, 65536);

  hipMemsetAsync(ws + YBUF_OFF, 0, 2097152, stream);   // tags=0, y_0=0 (both parities)

  horn_convert<<<8192, 256, 0, stream>>>(batch, (unsigned short*)(ws + 0));

  horn_persistent<<<128, THREADS, 65536, stream>>>(
      (const unsigned short*)(ws + 0), i2h_w, i2h_b, h2h_w, h2h_b,
      (unsigned*)(ws + YBUF_OFF), (float*)(ws + XT_OFF));

  horn_out<<<BATCH_N, 64, 0, stream>>>((const float*)(ws + XT_OFF), h2o_w, h2o_b, out);
}

// Round 11
// 1522.194 us; speedup vs baseline: 1.4144x; 1.4144x over previous
//
#include <hip/hip_runtime.h>

// ---------------- problem constants ----------------
#define T_STEPS 512
#define BATCH_N 256
#define IDIM    128
#define NDIM    1024
#define ODIM    10

// 256 WGs = 16 batch-groups (16 rows) x 16 col-slices (64 cols), 4 waves.
// R2's proven protocol shape (bf16 y double-buffer, publish+drain, per-WG
// flag, wv0-only poll + barrier release) with two fixes:
//   - poll = ONE coalesced plain sc0 sc1 load of the 16-flag line (no atomic
//     RMW serialization), flag lines padded to 128B/group.
//   - W in registers (R3/R9-proven wfrag[4][8]) -> no W LDS reads/conflicts.
#define THREADS 256
#define GAIN 0.03125f

// ---------------- workspace layout (bytes) ----------------
#define YBUF_OFF    (33554432ull)                 // after bf16 batch [512][256][128]
#define YBUF_HALF   (524288ull)                   // bytes per parity: bf16 [16][16][1024]
#define YHALF_EL    (262144u)                     // ushort elements per parity
#define FLG_OFF     (YBUF_OFF + 2*YBUF_HALF)
#define FLG_BYTES   (2048ull)                     // [16 groups][32 words] (16 used, 128B pad)
#define XT_OFF      (FLG_OFF + FLG_BYTES)
#define XT_BYTES    (1048576ull)                  // fp32 [256][1024]
#define WS_NEED     (XT_OFF + XT_BYTES)

typedef short    s16x8 __attribute__((ext_vector_type(8)));
typedef float    f32x4 __attribute__((ext_vector_type(4)));
typedef unsigned u32x4 __attribute__((ext_vector_type(4)));

__device__ __forceinline__ unsigned short f2bf(float f) {
  unsigned u = __builtin_bit_cast(unsigned, f);
  u += 0x7fffu + ((u >> 16) & 1u);               // RTNE
  return (unsigned short)(u >> 16);
}

// ---------------- batch fp32 -> bf16 prepass ----------------
__global__ void horn_convert(const float* __restrict__ src, unsigned short* __restrict__ dst) {
  size_t gid = (size_t)blockIdx.x * 256 + threadIdx.x;
  const f32x4* s4 = reinterpret_cast<const f32x4*>(src) + gid * 2;
  f32x4 a = s4[0], b = s4[1];
  u32x4 o;
  o[0] = (unsigned)f2bf(a[0]) | ((unsigned)f2bf(a[1]) << 16);
  o[1] = (unsigned)f2bf(a[2]) | ((unsigned)f2bf(a[3]) << 16);
  o[2] = (unsigned)f2bf(b[0]) | ((unsigned)f2bf(b[1]) << 16);
  o[3] = (unsigned)f2bf(b[2]) | ((unsigned)f2bf(b[3]) << 16);
  reinterpret_cast<u32x4*>(dst)[gid] = o;
}

// ---------------- persistent recurrent kernel ----------------
// LDS: y-stage bf16 [16 rows][1024], XOR-swizzled (32 KB) + red[4][4][64] f32x4 (16 KB)
__launch_bounds__(THREADS, 1)
__global__ void horn_persistent(const unsigned short* __restrict__ batchbf,
                                const float* __restrict__ i2h_w,
                                const float* __restrict__ i2h_b,
                                const float* __restrict__ h2h_w,
                                const float* __restrict__ h2h_b,
                                unsigned short* ybuf,     // bf16 [2][16][16][1024]
                                unsigned int*  flags,     // u32 [16][32] (16 used/group)
                                float* xT)                // [256][1024] fp32
{
  __shared__ char  ylds[32768];
  __shared__ f32x4 red[4][4][64];                  // [ki][ct][lane]

  const int tid  = threadIdx.x;
  const int lane = tid & 63;
  const int wv   = tid >> 6;          // wave 0..3: K-quarter wv, owned ct = wv
  const int blk  = blockIdx.x;
  const int ig   = blk & 15;          // batch group (16 rows)
  const int jg   = blk >> 4;          // col-slice 0..15 (64 cols)
  const int l15  = lane & 15;
  const int kb   = lane >> 4;
  const int jc   = jg * 64 + wv * 16 + l15;        // owned output column

  // ---- W fragments: 4 ct x 8 kc (K-quarter wv), xGAIN = 128 VGPRs ----
  s16x8 wfrag[4][8];
  #pragma unroll
  for (int ct = 0; ct < 4; ++ct) {
    #pragma unroll
    for (int kc = 0; kc < 8; ++kc) {
      const float* gp = h2h_w + (size_t)(jg * 64 + ct * 16 + l15) * NDIM
                        + wv * 256 + kc * 32 + kb * 8;
      f32x4 a = *reinterpret_cast<const f32x4*>(gp);
      f32x4 b = *reinterpret_cast<const f32x4*>(gp + 4);
      s16x8 v;
      v[0] = (short)f2bf(a[0]*GAIN); v[1] = (short)f2bf(a[1]*GAIN);
      v[2] = (short)f2bf(a[2]*GAIN); v[3] = (short)f2bf(a[3]*GAIN);
      v[4] = (short)f2bf(b[0]*GAIN); v[5] = (short)f2bf(b[1]*GAIN);
      v[6] = (short)f2bf(b[2]*GAIN); v[7] = (short)f2bf(b[3]*GAIN);
      wfrag[ct][kc] = v;
    }
  }

  // ---- i2h B-frags for owned column + fused bias ----
  s16x8 i2hf[4];
  #pragma unroll
  for (int kc = 0; kc < 4; ++kc) {
    const float* gp = i2h_w + (size_t)jc * IDIM + kc * 32 + kb * 8;
    s16x8 v;
    #pragma unroll
    for (int e = 0; e < 8; ++e) v[e] = (short)f2bf(gp[e]);
    i2hf[kc] = v;
  }
  const float bias = i2h_b[jc] + GAIN * h2h_b[jc];

  // ---- batch A-frags for t=0 ----
  s16x8 bfr[4];
  {
    const unsigned short* bp = batchbf + ((size_t)ig * 16 + l15) * IDIM + kb * 8;
    #pragma unroll
    for (int kc = 0; kc < 4; ++kc) bfr[kc] = *reinterpret_cast<const s16x8*>(bp + kc * 32);
  }

  float xs[4] = {0.f,0.f,0.f,0.f};
  float ys[4] = {0.f,0.f,0.f,0.f};

  const char* ytile = (const char*)ybuf + (size_t)ig * 32768;            // + p*YBUF_HALF
  unsigned short* pub0 = ybuf + (size_t)(ig * 16 + kb * 4) * 1024 + jc;  // + pn*YHALF_EL
  const unsigned* fline = flags + ig * 32 + l15;                         // 64B line, 1 req
  unsigned* fstore = flags + ig * 32 + jg;

  for (int t = 0; t < T_STEPS; ++t) {
    const int p = t & 1, pn = p ^ 1;

    // ---- poll (wv0 only, plain coalesced load of the flag line) ----
    if (t > 0) {
      if (wv == 0) {
        while (true) {
          unsigned fv;
          asm volatile("global_load_dword %0, %1, off sc0 sc1\n\t"
                       "s_waitcnt vmcnt(0)"
                       : "=v"(fv) : "v"(fline) : "memory");
          if (__all((int)fv >= t)) break;
          __builtin_amdgcn_s_sleep(1);
        }
      }
      __syncthreads();                             // barP: release all waves
    }

    // ---- coalesced gather of the 32KB y tile (16B/thread x 8 rounds) ----
    const char* q0 = ytile + (size_t)p * YBUF_HALF + tid * 16;
    u32x4 v0, v1, v2, v3, v4, v5, v6, v7;
    asm volatile(
      "global_load_dwordx4 %0, %8, off sc0 sc1\n\t"
      "global_load_dwordx4 %1, %9, off sc0 sc1\n\t"
      "global_load_dwordx4 %2, %10, off sc0 sc1\n\t"
      "global_load_dwordx4 %3, %11, off sc0 sc1\n\t"
      "global_load_dwordx4 %4, %12, off sc0 sc1\n\t"
      "global_load_dwordx4 %5, %13, off sc0 sc1\n\t"
      "global_load_dwordx4 %6, %14, off sc0 sc1\n\t"
      "global_load_dwordx4 %7, %15, off sc0 sc1"
      : "=&v"(v0), "=&v"(v1), "=&v"(v2), "=&v"(v3),
        "=&v"(v4), "=&v"(v5), "=&v"(v6), "=&v"(v7)
      : "v"(q0), "v"(q0 + 4096), "v"(q0 + 8192), "v"(q0 + 12288),
        "v"(q0 + 16384), "v"(q0 + 20480), "v"(q0 + 24576), "v"(q0 + 28672)
      : "memory");

    // ---- u-phase under the gather shadow ----
    f32x4 uacc = {bias, bias, bias, bias};
    #pragma unroll
    for (int kc = 0; kc < 4; ++kc)
      uacc = __builtin_amdgcn_mfma_f32_16x16x32_bf16(bfr[kc], i2hf[kc], uacc, 0, 0, 0);

    asm volatile("s_waitcnt vmcnt(0)" ::: "memory");
    __builtin_amdgcn_sched_barrier(0);             // rule #18

    // ---- stage to LDS, XOR-swizzled ----
    #define STG(r, vr) { int B_ = (r) * 4096 + tid * 16; int row_ = B_ >> 11; \
      *reinterpret_cast<u32x4*>(ylds + (B_ ^ ((row_ & 7) << 4))) = vr; }
    STG(0, v0) STG(1, v1) STG(2, v2) STG(3, v3)
    STG(4, v4) STG(5, v5) STG(6, v6) STG(7, v7)
    #undef STG
    __syncthreads();                               // bar1: tile ready

    // ---- rec partials: 4 ct x 8 kc MFMAs, A-frags from LDS ----
    f32x4 c0 = {0,0,0,0}, c1 = {0,0,0,0}, c2 = {0,0,0,0}, c3 = {0,0,0,0};
    #pragma unroll
    for (int kc = 0; kc < 8; ++kc) {
      int boff = (l15 * 2048 + wv * 512 + kc * 64 + kb * 16) ^ ((l15 & 7) << 4);
      s16x8 a = *reinterpret_cast<const s16x8*>(ylds + boff);
      c0 = __builtin_amdgcn_mfma_f32_16x16x32_bf16(a, wfrag[0][kc], c0, 0, 0, 0);
      c1 = __builtin_amdgcn_mfma_f32_16x16x32_bf16(a, wfrag[1][kc], c1, 0, 0, 0);
      c2 = __builtin_amdgcn_mfma_f32_16x16x32_bf16(a, wfrag[2][kc], c2, 0, 0, 0);
      c3 = __builtin_amdgcn_mfma_f32_16x16x32_bf16(a, wfrag[3][kc], c3, 0, 0, 0);
    }

    // ---- cross-wave K-reduction (single buffer; fenced by bar3/barP) ----
    red[wv][0][lane] = c0;
    red[wv][1][lane] = c1;
    red[wv][2][lane] = c2;
    red[wv][3][lane] = c3;
    __syncthreads();                               // bar2: partials ready
    f32x4 z = uacc;
    z += red[0][wv][lane];
    z += red[1][wv][lane];
    z += red[2][wv][lane];
    z += red[3][wv][lane];

    // ---- state update (fp32, fast tanh) ----
    unsigned yw0, yw1, yw2, yw3;
    {
      float zz, e, r, th, yn;
      zz = z[0]; e = __expf(zz + zz); r = __builtin_amdgcn_rcpf(e + 1.0f); th = fmaf(-2.0f, r, 1.0f);
      yn = ys[0] + 0.1f*(th - xs[0] - 0.2f*ys[0]); xs[0] += 0.1f*yn; ys[0] = yn; yw0 = f2bf(yn);
      zz = z[1]; e = __expf(zz + zz); r = __builtin_amdgcn_rcpf(e + 1.0f); th = fmaf(-2.0f, r, 1.0f);
      yn = ys[1] + 0.1f*(th - xs[1] - 0.2f*ys[1]); xs[1] += 0.1f*yn; ys[1] = yn; yw1 = f2bf(yn);
      zz = z[2]; e = __expf(zz + zz); r = __builtin_amdgcn_rcpf(e + 1.0f); th = fmaf(-2.0f, r, 1.0f);
      yn = ys[2] + 0.1f*(th - xs[2] - 0.2f*ys[2]); xs[2] += 0.1f*yn; ys[2] = yn; yw2 = f2bf(yn);
      zz = z[3]; e = __expf(zz + zz); r = __builtin_amdgcn_rcpf(e + 1.0f); th = fmaf(-2.0f, r, 1.0f);
      yn = ys[3] + 0.1f*(th - xs[3] - 0.2f*ys[3]); xs[3] += 0.1f*yn; ys[3] = yn; yw3 = f2bf(yn);
    }

    // ---- publish y_{t+1} (owned col, 4 rows); prefetch; drain; flag ----
    {
      unsigned short* b0 = pub0 + (size_t)pn * YHALF_EL;
      unsigned short* b1 = b0 + 2 * NDIM;
      asm volatile(
        "global_store_short %4, %0, off offset:0    sc0 sc1\n\t"
        "global_store_short %4, %1, off offset:2048 sc0 sc1\n\t"
        "global_store_short %5, %2, off offset:0    sc0 sc1\n\t"
        "global_store_short %5, %3, off offset:2048 sc0 sc1"
        :
        : "v"(yw0), "v"(yw1), "v"(yw2), "v"(yw3), "v"(b0), "v"(b1)
        : "memory");
    }
    {
      const int tn = (t + 1 < T_STEPS) ? (t + 1) : t;
      const unsigned short* bp = batchbf + ((size_t)tn * BATCH_N + ig * 16 + l15) * IDIM + kb * 8;
      #pragma unroll
      for (int kc = 0; kc < 4; ++kc) bfr[kc] = *reinterpret_cast<const s16x8*>(bp + kc * 32);
    }
    asm volatile("s_waitcnt vmcnt(0)" ::: "memory");   // publish acked (+prefetch done)
    __syncthreads();                               // bar3: whole WG drained
    if (tid == 0) {
      unsigned nv = (unsigned)(t + 1);
      asm volatile("global_store_dword %0, %1, off sc0 sc1"
                   :: "v"(fstore), "v"(nv) : "memory");
    }
  }

  // ---- write x_T (owned column, 4 rows) ----
  #pragma unroll
  for (int q = 0; q < 4; ++q) {
    int row = ig * 16 + kb * 4 + q;
    xT[(size_t)row * NDIM + jc] = xs[q];
  }
}

// ---------------- final readout: out = x_T @ h2o^T + b ----------------
__global__ void horn_out(const float* __restrict__ xT, const float* __restrict__ h2o_w,
                         const float* __restrict__ h2o_b, float* __restrict__ out) {
  int b = blockIdx.x;
  int lane = threadIdx.x;                  // 64 threads
  float p[ODIM];
  #pragma unroll
  for (int o = 0; o < ODIM; ++o) p[o] = 0.f;
  for (int it = 0; it < NDIM / 64; ++it) {
    int n = it * 64 + lane;
    float xv = xT[(size_t)b * NDIM + n];
    #pragma unroll
    for (int o = 0; o < ODIM; ++o) p[o] += xv * h2o_w[o * NDIM + n];
  }
  #pragma unroll
  for (int o = 0; o < ODIM; ++o) {
    float v = p[o];
    #pragma unroll
    for (int off = 32; off >= 1; off >>= 1) v += __shfl_down(v, off, 64);
    if (lane == 0) out[b * ODIM + o] = v + h2o_b[o];
  }
}

__global__ void horn_fail(float* out) {    // loud sentinel if ws too small
  int i = blockIdx.x * 256 + threadIdx.x;
  if (i < BATCH_N * ODIM) out[i] = 12345.0f;
}

extern "C" void kernel_launch(void* const* d_in, const int* in_sizes, int n_in,
                              void* d_out, int out_size, void* d_ws, size_t ws_size,
                              hipStream_t stream) {
  const float* batch = (const float*)d_in[0];
  const float* i2h_w = (const float*)d_in[1];
  const float* i2h_b = (const float*)d_in[2];
  const float* h2h_w = (const float*)d_in[3];
  const float* h2h_b = (const float*)d_in[4];
  const float* h2o_w = (const float*)d_in[5];
  const float* h2o_b = (const float*)d_in[6];
  float* out = (float*)d_out;
  char* ws = (char*)d_ws;

  if (ws_size < WS_NEED) {
    horn_fail<<<16, 256, 0, stream>>>(out);
    return;
  }

  hipMemsetAsync(ws + YBUF_OFF, 0, YBUF_HALF, stream);   // y_0 = 0 (parity 0)
  hipMemsetAsync(ws + FLG_OFF, 0, FLG_BYTES, stream);    // flags = 0

  horn_convert<<<8192, 256, 0, stream>>>(batch, (unsigned short*)(ws + 0));

  horn_persistent<<<256, THREADS, 0, stream>>>(
      (const unsigned short*)(ws + 0), i2h_w, i2h_b, h2h_w, h2h_b,
      (unsigned short*)(ws + YBUF_OFF), (unsigned int*)(ws + FLG_OFF),
      (float*)(ws + XT_OFF));

  horn_out<<<BATCH_N, 64, 0, stream>>>((const float*)(ws + XT_OFF), h2o_w, h2o_b, out);
}